// Round 1
// baseline (5186.089 us; speedup 1.0000x reference)
//
#include <hip/hip_runtime.h>

// NeuralPredictorModel: 3-layer GCN over B=65536 tiny graphs (GS=7), fused with
// pooling + fc1 + fc2.  Round 1: exact-fp32, wave-per-item baseline.
//
// Algebra exploited:
//   adj_d = row_norm(adj + I); row_norm(adj_d) == adj_d (rows already sum to 1)
//   inv_norm_adj = row_norm(adj_d^T) is the same for all 3 layers
//   x_{l+1} = 0.5*( relu(nA @ (x@w1)) + relu(iA @ (x@w2)) )
//   out = ((sum_rows(x3)/nv) @ fc1^T) @ fc2^T

constexpr int B    = 65536;
constexpr int GS   = 7;
constexpr int IN_H = 5;
constexpr int H    = 144;
constexpr int IPB  = 4;   // items (waves) per block

__global__ __launch_bounds__(256)
void gcn_fused(const float* __restrict__ ops, const float* __restrict__ adj,
               const float* __restrict__ nv,
               const float* __restrict__ w10, const float* __restrict__ w20,
               const float* __restrict__ w11, const float* __restrict__ w21,
               const float* __restrict__ w12, const float* __restrict__ w22,
               const float* __restrict__ fc1, const float* __restrict__ fc2,
               float* __restrict__ out)
{
    __shared__ float sx [IPB][GS][H];
    __shared__ float st1[IPB][GS][H];
    __shared__ float st2[IPB][GS][H];
    __shared__ float sA [IPB][2][GS][GS];   // [0]=norm_adj (adj_d), [1]=inv_norm_adj

    const int wv   = threadIdx.x >> 6;
    const int lane = threadIdx.x & 63;
    const int item = blockIdx.x * IPB + wv;

    // ---- load operations -> sx[.][i][0..4]
    if (lane < GS * IN_H) {
        sx[wv][lane / IN_H][lane % IN_H] = ops[(size_t)item * (GS * IN_H) + lane];
    }
    // ---- adj_d = row_normalize(adj + I): one row per lane (7 lanes active)
    if (lane < GS) {
        const int r = lane;
        float row[GS]; float s = 0.f;
        #pragma unroll
        for (int c = 0; c < GS; ++c) {
            float v = adj[(size_t)item * (GS * GS) + r * GS + c] + (c == r ? 1.f : 0.f);
            row[c] = v; s += v;
        }
        const float is = 1.f / s;
        #pragma unroll
        for (int c = 0; c < GS; ++c) sA[wv][0][r][c] = row[c] * is;
    }
    __syncthreads();
    // ---- inv_norm_adj = row_normalize(adj_d^T)
    if (lane < GS) {
        const int r = lane;                  // row r of adj_d^T == column r of adj_d
        float col[GS]; float s = 0.f;
        #pragma unroll
        for (int c = 0; c < GS; ++c) { float v = sA[wv][0][c][r]; col[c] = v; s += v; }
        const float is = 1.f / s;
        #pragma unroll
        for (int c = 0; c < GS; ++c) sA[wv][1][r][c] = col[c] * is;
    }
    __syncthreads();

    // ==================== 3 GCN layers ====================
    for (int layer = 0; layer < 3; ++layer) {
        if (layer == 0) {
            // t1 = x @ w10, t2 = x @ w20   (K = 5)
            for (int idx = lane; idx < GS * H; idx += 64) {
                const int i = idx / H, j = idx - i * H;
                float a = 0.f, b = 0.f;
                #pragma unroll
                for (int k = 0; k < IN_H; ++k) {
                    const float xv = sx[wv][i][k];
                    a = fmaf(xv, w10[k * H + j], a);
                    b = fmaf(xv, w20[k * H + j], b);
                }
                st1[wv][i][j] = a; st2[wv][i][j] = b;
            }
        } else {
            const float* __restrict__ W1 = (layer == 1) ? w11 : w12;
            const float* __restrict__ W2 = (layer == 1) ? w21 : w22;
            // 7 rows * 36 col-groups of 4 = 252 units; float4 weight loads
            for (int u = lane; u < GS * (H / 4); u += 64) {
                const int i  = u / (H / 4);
                const int j0 = (u - i * (H / 4)) * 4;
                float a0 = 0, a1 = 0, a2 = 0, a3 = 0;
                float b0 = 0, b1 = 0, b2 = 0, b3 = 0;
                #pragma unroll 4
                for (int k = 0; k < H; ++k) {
                    const float xv = sx[wv][i][k];
                    const float4 p = *(const float4*)(W1 + k * H + j0);
                    const float4 q = *(const float4*)(W2 + k * H + j0);
                    a0 = fmaf(xv, p.x, a0); a1 = fmaf(xv, p.y, a1);
                    a2 = fmaf(xv, p.z, a2); a3 = fmaf(xv, p.w, a3);
                    b0 = fmaf(xv, q.x, b0); b1 = fmaf(xv, q.y, b1);
                    b2 = fmaf(xv, q.z, b2); b3 = fmaf(xv, q.w, b3);
                }
                st1[wv][i][j0] = a0; st1[wv][i][j0 + 1] = a1;
                st1[wv][i][j0 + 2] = a2; st1[wv][i][j0 + 3] = a3;
                st2[wv][i][j0] = b0; st2[wv][i][j0 + 1] = b1;
                st2[wv][i][j0 + 2] = b2; st2[wv][i][j0 + 3] = b3;
            }
        }
        __syncthreads();

        // mixing: x = 0.5*( relu(nA@t1) + relu(iA@t2) )
        for (int idx = lane; idx < GS * H; idx += 64) {
            const int i = idx / H, j = idx - i * H;
            float a = 0.f, b = 0.f;
            #pragma unroll
            for (int k = 0; k < GS; ++k) {
                a = fmaf(sA[wv][0][i][k], st1[wv][k][j], a);
                b = fmaf(sA[wv][1][i][k], st2[wv][k][j], b);
            }
            a = a > 0.f ? a : 0.f;
            b = b > 0.f ? b : 0.f;
            sx[wv][i][j] = 0.5f * (a + b);
        }
        __syncthreads();
    }

    // ==================== pooling + fc1 + fc2 ====================
    const float nvv = nv[item];
    for (int j = lane; j < H; j += 64) {
        float s = 0.f;
        #pragma unroll
        for (int i = 0; i < GS; ++i) s += sx[wv][i][j];
        st1[wv][0][j] = s / nvv;            // pooled (reuse st1 row 0)
    }
    __syncthreads();

    // fc1: h[o] = pooled . fc1_w[o,:]  (o = lane and lane+64), no activation
    float h0 = 0.f, h1 = 0.f;
    for (int j = 0; j < H; ++j) {
        const float p = st1[wv][0][j];
        h0 = fmaf(p, fc1[(size_t)lane * H + j], h0);
        h1 = fmaf(p, fc1[(size_t)(lane + 64) * H + j], h1);
    }
    // fc2: out = h . fc2_w
    float v = fmaf(h0, fc2[lane], h1 * fc2[lane + 64]);
    #pragma unroll
    for (int off = 32; off > 0; off >>= 1) v += __shfl_down(v, off);
    if (lane == 0) out[item] = v;
}

extern "C" void kernel_launch(void* const* d_in, const int* in_sizes, int n_in,
                              void* d_out, int out_size, void* d_ws, size_t ws_size,
                              hipStream_t stream) {
    const float* ops = (const float*)d_in[0];
    const float* adj = (const float*)d_in[1];
    const float* nv  = (const float*)d_in[2];
    const float* w10 = (const float*)d_in[3];
    const float* w20 = (const float*)d_in[4];
    const float* w11 = (const float*)d_in[5];
    const float* w21 = (const float*)d_in[6];
    const float* w12 = (const float*)d_in[7];
    const float* w22 = (const float*)d_in[8];
    const float* fc1 = (const float*)d_in[9];
    const float* fc2 = (const float*)d_in[10];
    float* out = (float*)d_out;

    gcn_fused<<<B / IPB, 256, 0, stream>>>(ops, adj, nv,
                                           w10, w20, w11, w21, w12, w22,
                                           fc1, fc2, out);
}

// Round 3
// 855.039 us; speedup vs baseline: 6.0653x; 6.0653x over previous
//
#include <hip/hip_runtime.h>

// Fused 3-layer GCN (GS=7, H=144) + pool + fc, B=65536. Round 3: MFMA fp16,
// fixes R2's WAR hazard (pass-0 mixing overwrote sX while pass-1 GEMM still
// needed old x). Pass-0 x_new now goes to a stash aliased into sW rows 48-95
// (dead during pass 1), copied into sX at layer end.
//
// Structure per block (8 graphs, M=56 rows):
//   sX [64][152] fp16  : stacked node features, K-contiguous (B-operand)
//   sW [96][152] fp16  : transposed weight slab Wt[n][k]   (A-operand)
//   sT1[56][104] fp16  : T1 / P buffer (pass-local N<=96 cols)
//   sT2 aliases sW bytes [0,11648)      (barrier-protected)
//   sXn aliases sW bytes [14592,25344)  : stash for x_new[:,0:96] (56x96 fp16)
// N=144 in 2 passes (96 | 48); per pass two GEMM phases (W1,W2) then VALU
// mixing with per-item 7x7 adjacency. fc1/fc2 collapsed to g = fc2@fc1.
// MFMA (swapped operands): A[n][k]=Wt, B[k][m]=X -> D[n][m]=T[m][n];
// A/B: lane holds row/col lane&31, 8 contiguous k at (lane>>5)*8;
// C/D: col=lane&31 (=m), row=(reg&3)+8*(reg>>2)+4*(lane>>5) (=n).

typedef _Float16 half8  __attribute__((ext_vector_type(8)));
typedef _Float16 half4_t __attribute__((ext_vector_type(4)));
typedef float    floatx16 __attribute__((ext_vector_type(16)));

constexpr int GS = 7;
constexpr int NI = 8;           // graphs per block
constexpr int MROWS = NI * GS;  // 56
constexpr int H = 144;

static __device__ inline half8 bc(_Float16 v) {
    half8 h = {v, v, v, v, v, v, v, v};
    return h;
}

__global__ void g_kernel(const float* __restrict__ fc1, const float* __restrict__ fc2,
                         float* __restrict__ g) {
    const int j = threadIdx.x;
    if (j < H) {
        float s = 0.f;
        for (int o = 0; o < 128; ++o) s = fmaf(fc2[o], fc1[o * H + j], s);
        g[j] = s;
    }
}

__global__ __launch_bounds__(256, 2)
void gcn_mfma(const float* __restrict__ ops, const float* __restrict__ adj,
              const float* __restrict__ nv,
              const float* __restrict__ w10, const float* __restrict__ w20,
              const float* __restrict__ w11, const float* __restrict__ w21,
              const float* __restrict__ w12, const float* __restrict__ w22,
              const float* __restrict__ gw, float* __restrict__ out)
{
    __shared__ __align__(16) _Float16 sX[64][152];     // 19456 B
    __shared__ __align__(16) _Float16 sW[96][152];     // 29184 B
    __shared__ __align__(16) _Float16 sT1[MROWS][104]; // 11648 B   total 60288 B

    _Float16 (*sT2)[104] = (_Float16(*)[104])&sW[0][0];          // alias, bytes [0,11648)
    _Float16 (*sXn)[96]  = (_Float16(*)[96])((char*)&sW[0][0] + 14592); // sW rows 48+, 10752 B
    _Float16 (*sA)[2][GS][8] = (_Float16(*)[2][GS][8])&sX[MROWS][0];   // sX pad rows 56-63
    float (*adjd)[GS][GS] = (float(*)[GS][GS])&sT1[0][0];        // prologue-only scratch

    const int tid  = threadIdx.x;
    const int lane = tid & 63;
    const int wv   = tid >> 6;
    const int ibase = blockIdx.x * NI;

    // ---------------- prologue: stage X (fp16), adjacency matrices ----------------
    if (tid < MROWS) {
        const int item = tid / GS, r = tid % GS;
        const float* orow = ops + ((size_t)(ibase + item) * GS + r) * 5;
        half8 h = bc((_Float16)0);
        h[0] = (_Float16)orow[0]; h[1] = (_Float16)orow[1]; h[2] = (_Float16)orow[2];
        h[3] = (_Float16)orow[3]; h[4] = (_Float16)orow[4];
        *(half8*)&sX[tid][0] = h;
        *(half8*)&sX[tid][8] = bc((_Float16)0);   // zero k=8..15 (layer-0 K pad)

        const float* arow = adj + ((size_t)(ibase + item) * GS + r) * GS;
        float a[GS]; float s = 0.f;
        #pragma unroll
        for (int c = 0; c < GS; ++c) { a[c] = arow[c] + (c == r ? 1.f : 0.f); s += a[c]; }
        const float is = 1.f / s;
        #pragma unroll
        for (int c = 0; c < GS; ++c) {
            const float v = a[c] * is;
            adjd[item][r][c] = v;
            sA[item][0][r][c] = (_Float16)v;
        }
        sA[item][0][r][7] = (_Float16)0.f;
    }
    __syncthreads();
    if (tid < MROWS) {    // inv_norm_adj = row_normalize(adj_d^T)
        const int item = tid / GS, r = tid % GS;
        float v[GS]; float s = 0.f;
        #pragma unroll
        for (int k = 0; k < GS; ++k) { v[k] = adjd[item][k][r]; s += v[k]; }
        const float is = 1.f / s;
        #pragma unroll
        for (int k = 0; k < GS; ++k) sA[item][1][r][k] = (_Float16)(v[k] * is);
        sA[item][1][r][7] = (_Float16)0.f;
    }
    __syncthreads();

    const float* W1s[3] = {w10, w11, w12};
    const float* W2s[3] = {w20, w21, w22};

    const int mt   = wv & 1;
    const int mrow = mt * 32 + (lane & 31);
    const int arow31 = lane & 31;
    const int khi  = (lane >> 5) * 8;

    // ==================== 3 layers x 2 N-passes x 2 W-phases ====================
    for (int layer = 0; layer < 3; ++layer) {
        const int nk = (layer == 0) ? 1 : 9;
        for (int pass = 0; pass < 2; ++pass) {
            const int nb = pass ? 96 : 0;
            const int NT = pass ? 2 : 3;    // 32-wide N-tiles this pass
            const int NW = pass ? 48 : 96;  // real (staged) width
            const int JB = pass ? 6 : 12;   // 8-col mixing blocks
            const int t0   = (wv < 2) ? 0 : (NT - 1);   // this wave's first n-tile
            const int tcnt = (wv < 2) ? (NT - 1) : 1;   // and tile count (1 or 2)

            for (int ph = 0; ph < 2; ++ph) {
                const float* Wg = ph ? W2s[layer] : W1s[layer];

                // ---- stage sW[nl][k] = (fp16) W[k][nb+nl] (transpose on the fly)
                if (layer > 0) {
                    for (int nl = lane; nl < NW; nl += 64) {
                        const float* col = Wg + nb + nl;
                        #pragma unroll
                        for (int kk = 0; kk < 9; ++kk) {
                            const int k0 = kk * 16 + wv * 4;
                            half4_t h;
                            h[0] = (_Float16)col[(size_t)(k0 + 0) * H];
                            h[1] = (_Float16)col[(size_t)(k0 + 1) * H];
                            h[2] = (_Float16)col[(size_t)(k0 + 2) * H];
                            h[3] = (_Float16)col[(size_t)(k0 + 3) * H];
                            *(half4_t*)&sW[nl][k0] = h;
                        }
                    }
                } else {
                    for (int nl = tid; nl < NW; nl += 256) {
                        const float* col = Wg + nb + nl;
                        half8 h = bc((_Float16)0);
                        h[0] = (_Float16)col[0];
                        h[1] = (_Float16)col[H];
                        h[2] = (_Float16)col[2 * H];
                        h[3] = (_Float16)col[3 * H];
                        h[4] = (_Float16)col[4 * H];
                        *(half8*)&sW[nl][0] = h;
                        *(half8*)&sW[nl][8] = bc((_Float16)0);  // avoid NaN garbage * 0
                    }
                }
                __syncthreads();

                // ---- GEMM: acc[n-tile] over K (reads OLD x all pass long — the R2 bug fix)
                floatx16 acc0, acc1;
                #pragma unroll
                for (int i = 0; i < 16; ++i) { acc0[i] = 0.f; acc1[i] = 0.f; }
                for (int ks = 0; ks < nk; ++ks) {
                    const int ko = ks * 16 + khi;
                    const half8 bfrag = *(const half8*)&sX[mrow][ko];
                    const half8 a0 = *(const half8*)&sW[t0 * 32 + arow31][ko];
                    acc0 = __builtin_amdgcn_mfma_f32_32x32x16_f16(a0, bfrag, acc0, 0, 0, 0);
                    if (tcnt == 2) {
                        const half8 a1 = *(const half8*)&sW[(t0 + 1) * 32 + arow31][ko];
                        acc1 = __builtin_amdgcn_mfma_f32_32x32x16_f16(a1, bfrag, acc1, 0, 0, 0);
                    }
                }

                if (ph == 1) __syncthreads();   // all GEMM2 reads of sW done before aliased store

                // ---- store T (packed half4 -> b64), D[n][m]: col=m=lane&31, row-n per reg
                _Float16 (*T)[104] = ph ? sT2 : sT1;
                if (mrow < MROWS) {
                    #pragma unroll
                    for (int ti = 0; ti < 2; ++ti) {
                        if (ti < tcnt) {
                            const floatx16& A = ti ? acc1 : acc0;
                            const int ntl = (t0 + ti) * 32 + 4 * (lane >> 5);
                            #pragma unroll
                            for (int q = 0; q < 4; ++q) {
                                const int nl = ntl + 8 * q;
                                if (nb + nl < H) {
                                    half4_t h;
                                    h[0] = (_Float16)A[4 * q + 0];
                                    h[1] = (_Float16)A[4 * q + 1];
                                    h[2] = (_Float16)A[4 * q + 2];
                                    h[3] = (_Float16)A[4 * q + 3];
                                    *(half4_t*)&T[mrow][nl] = h;
                                }
                            }
                        }
                    }
                }
                __syncthreads();

                // ---- mixing
                if (ph == 0) {
                    // in-place: P = relu(nA @ T1)
                    for (int u = tid; u < NI * JB; u += 256) {
                        const int item = u / JB, jb = u - item * JB;
                        const int c0 = jb * 8;
                        half8 r[GS];
                        #pragma unroll
                        for (int k = 0; k < GS; ++k)
                            r[k] = *(const half8*)&sT1[item * GS + k][c0];
                        #pragma unroll
                        for (int i = 0; i < GS; ++i) {
                            const half8 ar = *(const half8*)&sA[item][0][i][0];
                            half8 o = bc(ar[0]) * r[0];
                            #pragma unroll
                            for (int k = 1; k < GS; ++k) o += bc(ar[k]) * r[k];
                            #pragma unroll
                            for (int j = 0; j < 8; ++j)
                                if (o[j] < (_Float16)0) o[j] = (_Float16)0;
                            *(half8*)&sT1[item * GS + i][c0] = o;
                        }
                    }
                    // no barrier: next step writes sW rows 0..NW-1 only; sT1
                    // consumers are behind the post-staging barrier
                } else {
                    // x_new = 0.5 * (P + relu(iA @ T2))
                    // pass 0 -> stash sXn (old sX cols 0..95 still needed by pass 1!)
                    // pass 1 -> sX[:, 96:144] directly (last GEMM of layer is done)
                    for (int u = tid; u < NI * JB; u += 256) {
                        const int item = u / JB, jb = u - item * JB;
                        const int c0 = jb * 8;
                        half8 r[GS], p[GS];
                        #pragma unroll
                        for (int k = 0; k < GS; ++k) {
                            r[k] = *(const half8*)&sT2[item * GS + k][c0];
                            p[k] = *(const half8*)&sT1[item * GS + k][c0];
                        }
                        #pragma unroll
                        for (int i = 0; i < GS; ++i) {
                            const half8 ar = *(const half8*)&sA[item][1][i][0];
                            half8 o = bc(ar[0]) * r[0];
                            #pragma unroll
                            for (int k = 1; k < GS; ++k) o += bc(ar[k]) * r[k];
                            #pragma unroll
                            for (int j = 0; j < 8; ++j)
                                if (o[j] < (_Float16)0) o[j] = (_Float16)0;
                            const half8 x = (p[i] + o) * bc((_Float16)0.5f);
                            if (pass == 0) *(half8*)&sXn[item * GS + i][c0] = x;
                            else           *(half8*)&sX [item * GS + i][96 + c0] = x;
                        }
                    }
                    __syncthreads();
                }
            } // ph
        } // pass

        // ---- layer epilogue: commit stashed x_new[:, 0:96] into sX
        for (int u = tid; u < MROWS * 12; u += 256) {
            const int r = u / 12, c = (u - r * 12) * 8;
            *(half8*)&sX[r][c] = *(const half8*)&sXn[r][c];
        }
        __syncthreads();
    } // layer

    // ==================== pool + (fc2@fc1) dot ====================
    if (tid < NI * 16) {
        const int item = tid >> 4, part = tid & 15;
        float s = 0.f;
        #pragma unroll
        for (int c = 0; c < 9; ++c) {
            const int j = part * 9 + c;
            const float gj = gw[j];
            #pragma unroll
            for (int i = 0; i < GS; ++i)
                s = fmaf((float)sX[item * GS + i][j], gj, s);
        }
        s += __shfl_xor(s, 1);
        s += __shfl_xor(s, 2);
        s += __shfl_xor(s, 4);
        s += __shfl_xor(s, 8);
        if (part == 0) out[ibase + item] = s / nv[ibase + item];
    }
}

extern "C" void kernel_launch(void* const* d_in, const int* in_sizes, int n_in,
                              void* d_out, int out_size, void* d_ws, size_t ws_size,
                              hipStream_t stream) {
    const float* ops = (const float*)d_in[0];
    const float* adj = (const float*)d_in[1];
    const float* nv  = (const float*)d_in[2];
    const float* w10 = (const float*)d_in[3];
    const float* w20 = (const float*)d_in[4];
    const float* w11 = (const float*)d_in[5];
    const float* w21 = (const float*)d_in[6];
    const float* w12 = (const float*)d_in[7];
    const float* w22 = (const float*)d_in[8];
    const float* fc1 = (const float*)d_in[9];
    const float* fc2 = (const float*)d_in[10];
    float* gws = (float*)d_ws;
    float* out = (float*)d_out;

    g_kernel<<<1, 256, 0, stream>>>(fc1, fc2, gws);
    gcn_mfma<<<65536 / NI, 256, 0, stream>>>(ops, adj, nv,
                                             w10, w20, w11, w21, w12, w22,
                                             gws, out);
}

// Round 4
// 524.088 us; speedup vs baseline: 9.8955x; 1.6315x over previous
//
#include <hip/hip_runtime.h>

// Fused 3-layer GCN (GS=7, H=144) + pool + fc, B=65536.  Round 4.
// R3 was latency/barrier-bound (MfmaUtil 5%, VALUBusy 27%): per-block scalar
// fp32 weight loads + cvt on a ~38-barrier critical path. R4:
//  - prologue kernel pre-converts weights ONCE to fp16, transposed to MFMA
//    A-layout, W1/W2 column-interleaved: wt[l][n=2j+p][k]  (d_ws, L2-resident)
//  - per layer one N-sweep over 3 chunks of 96 interleaved cols (W1|W2 fused
//    in a single GEMM); mixing is chunk-local
//  - x_new kept in registers until the layer's last GEMM has read old x
//    (no stash buffer, no copy step, no WAR hazard)
//  - 2 barriers per chunk -> 21 total (was ~38)
// MFMA mapping (verified in R3): A[n][k]=Wt, B[k][m]=X -> D[n][m]=T[m][n];
// A/B: lane holds row/col lane&31, 8 contiguous k at (lane>>5)*8;
// C/D: col=lane&31 (=m), row=(reg&3)+8*(reg>>2)+4*(lane>>5) (=n).

typedef _Float16 half8   __attribute__((ext_vector_type(8)));
typedef _Float16 half4_t __attribute__((ext_vector_type(4)));
typedef _Float16 half2_t __attribute__((ext_vector_type(2)));
typedef float    floatx16 __attribute__((ext_vector_type(16)));

constexpr int GS = 7;
constexpr int NI = 8;           // graphs per block
constexpr int MROWS = NI * GS;  // 56
constexpr int H = 144;
constexpr int WT_HALFS = 3 * 288 * 144;   // 124416

static __device__ inline half8 bc(_Float16 v) {
    half8 h = {v, v, v, v, v, v, v, v};
    return h;
}

// ---------------- prologue: weights -> fp16 A-layout, g = fc2 @ fc1 ----------------
__global__ void prep_kernel(const float* __restrict__ w10, const float* __restrict__ w20,
                            const float* __restrict__ w11, const float* __restrict__ w21,
                            const float* __restrict__ w12, const float* __restrict__ w22,
                            const float* __restrict__ fc1, const float* __restrict__ fc2,
                            _Float16* __restrict__ wt, float* __restrict__ g)
{
    const int gidx = blockIdx.x * 256 + threadIdx.x;
    if (gidx < WT_HALFS) {
        const int l   = gidx / (288 * 144);
        const int rem = gidx - l * (288 * 144);
        const int n   = rem / 144;
        const int k   = rem - n * 144;
        const int j   = n >> 1;
        const int p   = n & 1;
        const float* W = (l == 0) ? (p ? w20 : w10)
                       : (l == 1) ? (p ? w21 : w11)
                                  : (p ? w22 : w12);
        const int K = (l == 0) ? 5 : 144;
        wt[gidx] = (k < K) ? (_Float16)W[k * H + j] : (_Float16)0.f;
    }
    if (blockIdx.x == WT_HALFS / 256 && threadIdx.x < H) {
        const int j = threadIdx.x;
        float s = 0.f;
        for (int o = 0; o < 128; ++o) s = fmaf(fc2[o], fc1[o * H + j], s);
        g[j] = s;
    }
}

__global__ __launch_bounds__(256, 2)
void gcn_mfma(const float* __restrict__ ops, const float* __restrict__ adj,
              const float* __restrict__ nv,
              const _Float16* __restrict__ wt, const float* __restrict__ gw,
              float* __restrict__ out)
{
    __shared__ __align__(16) _Float16 sX[64][152];     // 19456 B (rows 56-63: sA)
    __shared__ __align__(16) _Float16 sW[96][152];     // 29184 B
    __shared__ __align__(16) _Float16 sT[MROWS][104];  // 11648 B   total 60288 B

    _Float16 (*sA)[2][GS][8] = (_Float16(*)[2][GS][8])&sX[MROWS][0];  // sX pad rows
    float (*adjd)[GS][GS] = (float(*)[GS][GS])&sT[0][0];              // prologue-only

    const int tid  = threadIdx.x;
    const int lane = tid & 63;
    const int wv   = tid >> 6;
    const int ibase = blockIdx.x * NI;

    // ---------------- per-block prologue: stage X (fp16), adjacency matrices ----------------
    if (tid < MROWS) {
        const int item = tid / GS, r = tid % GS;
        const float* orow = ops + ((size_t)(ibase + item) * GS + r) * 5;
        half8 h = bc((_Float16)0);
        h[0] = (_Float16)orow[0]; h[1] = (_Float16)orow[1]; h[2] = (_Float16)orow[2];
        h[3] = (_Float16)orow[3]; h[4] = (_Float16)orow[4];
        *(half8*)&sX[tid][0] = h;
        *(half8*)&sX[tid][8] = bc((_Float16)0);   // layer-0 K pad

        const float* arow = adj + ((size_t)(ibase + item) * GS + r) * GS;
        float a[GS]; float s = 0.f;
        #pragma unroll
        for (int c = 0; c < GS; ++c) { a[c] = arow[c] + (c == r ? 1.f : 0.f); s += a[c]; }
        const float is = 1.f / s;
        #pragma unroll
        for (int c = 0; c < GS; ++c) {
            const float v = a[c] * is;
            adjd[item][r][c] = v;
            sA[item][0][r][c] = (_Float16)v;
        }
        sA[item][0][r][7] = (_Float16)0.f;
    }
    __syncthreads();
    if (tid < MROWS) {    // inv_norm_adj = row_normalize(adj_d^T)
        const int item = tid / GS, r = tid % GS;
        float v[GS]; float s = 0.f;
        #pragma unroll
        for (int k = 0; k < GS; ++k) { v[k] = adjd[item][k][r]; s += v[k]; }
        const float is = 1.f / s;
        #pragma unroll
        for (int k = 0; k < GS; ++k) sA[item][1][r][k] = (_Float16)(v[k] * is);
        sA[item][1][r][7] = (_Float16)0.f;
    }
    __syncthreads();

    const int mt     = wv & 1;
    const int arow31 = lane & 31;
    const int mrow   = mt * 32 + arow31;
    const int khi    = (lane >> 5) * 8;
    const int t0     = (wv < 2) ? 0 : 2;    // wave's first n-tile in chunk
    const int tcnt   = (wv < 2) ? 2 : 1;    // n-tiles this wave owns

    // mix-thread identity (threads 0..191)
    const int mitem = tid / 24;
    const int mb    = tid - mitem * 24;     // jj-pair index 0..23
    half2_t xr0[GS], xr1[GS];               // x_new stash for chunks 0,1

    // ==================== 3 layers x 3 n-chunks ====================
    for (int layer = 0; layer < 3; ++layer) {
        const int nk = (layer == 0) ? 1 : 9;
        const _Float16* wl = wt + layer * (288 * 144);

        for (int chunk = 0; chunk < 3; ++chunk) {
            // ---- stage sW[nl][k] <- wt rows (pure fp16 vector copy)
            const _Float16* wc = wl + chunk * (96 * 144);
            if (layer == 0) {
                for (int u = tid; u < 96 * 2; u += 256) {
                    const int r = u >> 1, kg = u & 1;
                    *(half8*)&sW[r][kg * 8] = *(const half8*)&wc[r * 144 + kg * 8];
                }
            } else {
                for (int u = tid; u < 96 * 18; u += 256) {
                    const int r = u / 18, kg = u - r * 18;
                    *(half8*)&sW[r][kg * 8] = *(const half8*)&wc[r * 144 + kg * 8];
                }
            }
            __syncthreads();   // B1: stage done; also orders prev mix before T-store

            // ---- GEMM: T[m][n] for this chunk's 96 interleaved cols
            floatx16 acc0, acc1;
            #pragma unroll
            for (int i = 0; i < 16; ++i) { acc0[i] = 0.f; acc1[i] = 0.f; }
            for (int ks = 0; ks < nk; ++ks) {
                const int ko = ks * 16 + khi;
                const half8 bfrag = *(const half8*)&sX[mrow][ko];
                const half8 a0 = *(const half8*)&sW[t0 * 32 + arow31][ko];
                acc0 = __builtin_amdgcn_mfma_f32_32x32x16_f16(a0, bfrag, acc0, 0, 0, 0);
                if (tcnt == 2) {
                    const half8 a1 = *(const half8*)&sW[(t0 + 1) * 32 + arow31][ko];
                    acc1 = __builtin_amdgcn_mfma_f32_32x32x16_f16(a1, bfrag, acc1, 0, 0, 0);
                }
            }

            // ---- store T (packed half4), D row n = (reg&3)+8*(reg>>2)+4*(lane>>5)
            if (mrow < MROWS) {
                #pragma unroll
                for (int ti = 0; ti < 2; ++ti) {
                    if (ti < tcnt) {
                        const floatx16& A = ti ? acc1 : acc0;
                        const int ntl = (t0 + ti) * 32 + 4 * (lane >> 5);
                        #pragma unroll
                        for (int q = 0; q < 4; ++q) {
                            half4_t h;
                            h[0] = (_Float16)A[4 * q + 0];
                            h[1] = (_Float16)A[4 * q + 1];
                            h[2] = (_Float16)A[4 * q + 2];
                            h[3] = (_Float16)A[4 * q + 3];
                            *(half4_t*)&sT[mrow][ntl + 8 * q] = h;
                        }
                    }
                }
            }
            __syncthreads();   // B2: T complete; also = last GEMM read of old sX

            // ---- mixing (chunk-local 48 cols): x = 0.5*(relu(nA@T1)+relu(iA@T2))
            // sT row layout: local n = 2*jj + p  (p=0 -> T1, p=1 -> T2), jj in [0,48)
            if (tid < 192) {
                const int row0 = mitem * GS;
                half2_t e[GS], o[GS];
                #pragma unroll
                for (int k = 0; k < GS; ++k) {
                    const half4_t c = *(const half4_t*)&sT[row0 + k][mb * 4];
                    e[k] = __builtin_shufflevector(c, c, 0, 2);   // T1 cols jj=2mb,2mb+1
                    o[k] = __builtin_shufflevector(c, c, 1, 3);   // T2 cols
                }
                #pragma unroll
                for (int i = 0; i < GS; ++i) {
                    const half8 aN = *(const half8*)&sA[mitem][0][i][0];
                    const half8 aI = *(const half8*)&sA[mitem][1][i][0];
                    half2_t s1 = {(_Float16)0, (_Float16)0};
                    half2_t s2 = {(_Float16)0, (_Float16)0};
                    #pragma unroll
                    for (int k = 0; k < GS; ++k) {
                        const half2_t bN = {aN[k], aN[k]};
                        const half2_t bI = {aI[k], aI[k]};
                        s1 += bN * e[k];
                        s2 += bI * o[k];
                    }
                    if (s1[0] < (_Float16)0) s1[0] = (_Float16)0;
                    if (s1[1] < (_Float16)0) s1[1] = (_Float16)0;
                    if (s2[0] < (_Float16)0) s2[0] = (_Float16)0;
                    if (s2[1] < (_Float16)0) s2[1] = (_Float16)0;
                    const half2_t x = (s1 + s2) * (half2_t){(_Float16)0.5f, (_Float16)0.5f};
                    if (chunk == 0)      xr0[i] = x;
                    else if (chunk == 1) xr1[i] = x;
                    else {
                        // layer's GEMMs all done (B2) -> safe to write sX
                        *(half2_t*)&sX[row0 + i][96 + 2 * mb] = x;
                        *(half2_t*)&sX[row0 + i][      2 * mb] = xr0[i];
                        *(half2_t*)&sX[row0 + i][ 48 + 2 * mb] = xr1[i];
                    }
                }
            }
            // next chunk's B1 (or final barrier) orders these writes
        } // chunk
    } // layer
    __syncthreads();   // x final in sX

    // ==================== pool + (fc2@fc1) dot ====================
    if (tid < NI * 16) {
        const int item = tid >> 4, part = tid & 15;
        float s = 0.f;
        #pragma unroll
        for (int c = 0; c < 9; ++c) {
            const int j = part * 9 + c;
            const float gj = gw[j];
            #pragma unroll
            for (int i = 0; i < GS; ++i)
                s = fmaf((float)sX[item * GS + i][j], gj, s);
        }
        s += __shfl_xor(s, 1);
        s += __shfl_xor(s, 2);
        s += __shfl_xor(s, 4);
        s += __shfl_xor(s, 8);
        if (part == 0) out[ibase + item] = s / nv[ibase + item];
    }
}

extern "C" void kernel_launch(void* const* d_in, const int* in_sizes, int n_in,
                              void* d_out, int out_size, void* d_ws, size_t ws_size,
                              hipStream_t stream) {
    const float* ops = (const float*)d_in[0];
    const float* adj = (const float*)d_in[1];
    const float* nv  = (const float*)d_in[2];
    const float* w10 = (const float*)d_in[3];
    const float* w20 = (const float*)d_in[4];
    const float* w11 = (const float*)d_in[5];
    const float* w21 = (const float*)d_in[6];
    const float* w12 = (const float*)d_in[7];
    const float* w22 = (const float*)d_in[8];
    const float* fc1 = (const float*)d_in[9];
    const float* fc2 = (const float*)d_in[10];

    _Float16* wt = (_Float16*)d_ws;                              // 248832 B
    float*    g  = (float*)((char*)d_ws + (size_t)WT_HALFS * 2); // 576 B

    prep_kernel<<<WT_HALFS / 256 + 1, 256, 0, stream>>>(w10, w20, w11, w21, w12, w22,
                                                        fc1, fc2, wt, g);
    gcn_mfma<<<65536 / NI, 256, 0, stream>>>(ops, adj, nv, wt, g, (float*)d_out);
}

// Round 5
// 357.297 us; speedup vs baseline: 14.5148x; 1.4668x over previous
//
#include <hip/hip_runtime.h>

// Fused 3-layer GCN (GS=7, H=144) + pool + fc, B=65536.  Round 5.
// R4 was latency-bound on the LDS weight-staging critical path (MfmaUtil 8%,
// VALUBusy 31%, 2 blocks/CU). R5 removes W staging entirely:
//  - wt (d_ws) is pre-transposed to MFMA A-fragment layout by prep_kernel, so
//    GEMM reads A-operands DIRECTLY from global (L1/L2-hot, no LDS, no stage
//    barrier). B-operands (x rows) load once per layer into registers.
//  - LDS = sX (19.5 KB) + sT (11.6 KB) = 31.1 KB -> 3+ blocks/CU.
//  - 2 barriers per chunk (T-store visibility, sT WAR), short sections.
// MFMA mapping (verified R3/R4): A[n][k]=Wt, B[k][m]=X -> D[n][m]=T[m][n];
// A/B: lane holds row/col lane&31, 8 contiguous k at (lane>>5)*8;
// C/D: col=lane&31 (=m), row=(reg&3)+8*(reg>>2)+4*(lane>>5) (=n).

typedef _Float16 half8   __attribute__((ext_vector_type(8)));
typedef _Float16 half4_t __attribute__((ext_vector_type(4)));
typedef _Float16 half2_t __attribute__((ext_vector_type(2)));
typedef float    floatx16 __attribute__((ext_vector_type(16)));

constexpr int GS = 7;
constexpr int NI = 8;           // graphs per block
constexpr int MROWS = NI * GS;  // 56
constexpr int H = 144;
constexpr int WT_HALFS = 3 * 288 * 144;   // 124416

static __device__ inline half8 bc(_Float16 v) {
    half8 h = {v, v, v, v, v, v, v, v};
    return h;
}

// ---------------- prologue: weights -> fp16 A-layout, g = fc2 @ fc1 ----------------
__global__ void prep_kernel(const float* __restrict__ w10, const float* __restrict__ w20,
                            const float* __restrict__ w11, const float* __restrict__ w21,
                            const float* __restrict__ w12, const float* __restrict__ w22,
                            const float* __restrict__ fc1, const float* __restrict__ fc2,
                            _Float16* __restrict__ wt, float* __restrict__ g)
{
    const int gidx = blockIdx.x * 256 + threadIdx.x;
    if (gidx < WT_HALFS) {
        const int l   = gidx / (288 * 144);
        const int rem = gidx - l * (288 * 144);
        const int n   = rem / 144;
        const int k   = rem - n * 144;
        const int j   = n >> 1;
        const int p   = n & 1;
        const float* W = (l == 0) ? (p ? w20 : w10)
                       : (l == 1) ? (p ? w21 : w11)
                                  : (p ? w22 : w12);
        const int K = (l == 0) ? 5 : 144;
        wt[gidx] = (k < K) ? (_Float16)W[k * H + j] : (_Float16)0.f;
    }
    if (blockIdx.x == WT_HALFS / 256 && threadIdx.x < H) {
        const int j = threadIdx.x;
        float s = 0.f;
        for (int o = 0; o < 128; ++o) s = fmaf(fc2[o], fc1[o * H + j], s);
        g[j] = s;
    }
}

__global__ __launch_bounds__(256, 3)
void gcn_mfma(const float* __restrict__ ops, const float* __restrict__ adj,
              const float* __restrict__ nv,
              const _Float16* __restrict__ wt, const float* __restrict__ gw,
              float* __restrict__ out)
{
    __shared__ __align__(16) _Float16 sX[64][152];     // 19456 B (rows 56-63: sA)
    __shared__ __align__(16) _Float16 sT[MROWS][104];  // 11648 B   total 31104 B

    _Float16 (*sA)[2][GS][8] = (_Float16(*)[2][GS][8])&sX[MROWS][0];  // sX pad rows
    float (*adjd)[GS][GS] = (float(*)[GS][GS])&sT[0][0];              // prologue-only

    const int tid  = threadIdx.x;
    const int lane = tid & 63;
    const int wv   = tid >> 6;
    const int ibase = blockIdx.x * NI;

    // ---------------- per-block prologue: stage X (fp16), adjacency matrices ----------------
    if (tid < MROWS) {
        const int item = tid / GS, r = tid % GS;
        const float* orow = ops + ((size_t)(ibase + item) * GS + r) * 5;
        half8 h = bc((_Float16)0);
        h[0] = (_Float16)orow[0]; h[1] = (_Float16)orow[1]; h[2] = (_Float16)orow[2];
        h[3] = (_Float16)orow[3]; h[4] = (_Float16)orow[4];
        *(half8*)&sX[tid][0] = h;
        *(half8*)&sX[tid][8] = bc((_Float16)0);   // layer-0 K pad

        const float* arow = adj + ((size_t)(ibase + item) * GS + r) * GS;
        float a[GS]; float s = 0.f;
        #pragma unroll
        for (int c = 0; c < GS; ++c) { a[c] = arow[c] + (c == r ? 1.f : 0.f); s += a[c]; }
        const float is = 1.f / s;
        #pragma unroll
        for (int c = 0; c < GS; ++c) {
            const float v = a[c] * is;
            adjd[item][r][c] = v;
            sA[item][0][r][c] = (_Float16)v;
        }
        sA[item][0][r][7] = (_Float16)0.f;
    }
    __syncthreads();
    if (tid < MROWS) {    // inv_norm_adj = row_normalize(adj_d^T)
        const int item = tid / GS, r = tid % GS;
        float v[GS]; float s = 0.f;
        #pragma unroll
        for (int k = 0; k < GS; ++k) { v[k] = adjd[item][k][r]; s += v[k]; }
        const float is = 1.f / s;
        #pragma unroll
        for (int k = 0; k < GS; ++k) sA[item][1][r][k] = (_Float16)(v[k] * is);
        sA[item][1][r][7] = (_Float16)0.f;
    }
    __syncthreads();

    const int mt     = wv & 1;
    const int arow31 = lane & 31;
    const int mrow   = mt * 32 + arow31;
    const int khi    = (lane >> 5) * 8;
    const int t0     = (wv < 2) ? 0 : 2;    // wave's first n-tile in chunk
    const int tcnt   = (wv < 2) ? 2 : 1;    // n-tiles this wave owns

    // mix-thread identity (threads 0..191)
    const int mitem = tid / 24;
    const int mb    = tid - mitem * 24;     // jj-pair index 0..23
    half2_t xr0[GS], xr1[GS];               // x_new stash for chunks 0,1

    // ==================== 3 layers x 3 n-chunks ====================
    for (int layer = 0; layer < 3; ++layer) {
        const int nk = (layer == 0) ? 1 : 9;
        const _Float16* wl = wt + layer * (288 * 144);

        // ---- B-fragments for this layer: x rows, once, into registers
        half8 bf[9];
        #pragma unroll
        for (int ks = 0; ks < 9; ++ks)
            if (ks < nk) bf[ks] = *(const half8*)&sX[mrow][ks * 16 + khi];

        for (int chunk = 0; chunk < 3; ++chunk) {
            // ---- GEMM: A straight from global (wt is A-layout), B from regs
            const _Float16* a0p = wl + chunk * (96 * 144) + (t0 * 32 + arow31) * 144 + khi;
            const _Float16* a1p = a0p + 32 * 144;
            floatx16 acc0, acc1;
            #pragma unroll
            for (int i = 0; i < 16; ++i) { acc0[i] = 0.f; acc1[i] = 0.f; }
            #pragma unroll
            for (int ks = 0; ks < 9; ++ks) {
                if (ks < nk) {
                    const half8 a0 = *(const half8*)(a0p + ks * 16);
                    acc0 = __builtin_amdgcn_mfma_f32_32x32x16_f16(a0, bf[ks], acc0, 0, 0, 0);
                    if (tcnt == 2) {
                        const half8 a1 = *(const half8*)(a1p + ks * 16);
                        acc1 = __builtin_amdgcn_mfma_f32_32x32x16_f16(a1, bf[ks], acc1, 0, 0, 0);
                    }
                }
            }

            if (chunk) __syncthreads();   // Ba: prev mix done reading sT

            // ---- store T (packed half4), D row n = (reg&3)+8*(reg>>2)+4*(lane>>5)
            if (mrow < MROWS) {
                #pragma unroll
                for (int ti = 0; ti < 2; ++ti) {
                    if (ti < tcnt) {
                        const floatx16& A = ti ? acc1 : acc0;
                        const int ntl = (t0 + ti) * 32 + 4 * (lane >> 5);
                        #pragma unroll
                        for (int q = 0; q < 4; ++q) {
                            half4_t h;
                            h[0] = (_Float16)A[4 * q + 0];
                            h[1] = (_Float16)A[4 * q + 1];
                            h[2] = (_Float16)A[4 * q + 2];
                            h[3] = (_Float16)A[4 * q + 3];
                            *(half4_t*)&sT[mrow][ntl + 8 * q] = h;
                        }
                    }
                }
            }
            __syncthreads();   // Bb: T visible to mixers

            // ---- mixing (chunk-local 48 cols): x = 0.5*(relu(nA@T1)+relu(iA@T2))
            // sT row layout: local n = 2*jj + p  (p=0 -> T1, p=1 -> T2), jj in [0,48)
            if (tid < 192) {
                const int row0 = mitem * GS;
                half2_t e[GS], o[GS];
                #pragma unroll
                for (int k = 0; k < GS; ++k) {
                    const half4_t c = *(const half4_t*)&sT[row0 + k][mb * 4];
                    e[k] = __builtin_shufflevector(c, c, 0, 2);   // T1 cols jj=2mb,2mb+1
                    o[k] = __builtin_shufflevector(c, c, 1, 3);   // T2 cols
                }
                #pragma unroll
                for (int i = 0; i < GS; ++i) {
                    const half8 aN = *(const half8*)&sA[mitem][0][i][0];
                    const half8 aI = *(const half8*)&sA[mitem][1][i][0];
                    half2_t s1 = {(_Float16)0, (_Float16)0};
                    half2_t s2 = {(_Float16)0, (_Float16)0};
                    #pragma unroll
                    for (int k = 0; k < GS; ++k) {
                        const half2_t bN = {aN[k], aN[k]};
                        const half2_t bI = {aI[k], aI[k]};
                        s1 += bN * e[k];
                        s2 += bI * o[k];
                    }
                    if (s1[0] < (_Float16)0) s1[0] = (_Float16)0;
                    if (s1[1] < (_Float16)0) s1[1] = (_Float16)0;
                    if (s2[0] < (_Float16)0) s2[0] = (_Float16)0;
                    if (s2[1] < (_Float16)0) s2[1] = (_Float16)0;
                    const half2_t x = (s1 + s2) * (half2_t){(_Float16)0.5f, (_Float16)0.5f};
                    if (chunk == 0)      xr0[i] = x;
                    else if (chunk == 1) xr1[i] = x;
                    else {
                        // all GEMM B-reads of this layer were done at layer start
                        *(half2_t*)&sX[row0 + i][96 + 2 * mb] = x;
                        *(half2_t*)&sX[row0 + i][      2 * mb] = xr0[i];
                        *(half2_t*)&sX[row0 + i][ 48 + 2 * mb] = xr1[i];
                    }
                }
            }
        } // chunk
        __syncthreads();   // Bc: new sX visible for next layer's B-frag loads / pool
    } // layer

    // ==================== pool + (fc2@fc1) dot ====================
    if (tid < NI * 16) {
        const int item = tid >> 4, part = tid & 15;
        float s = 0.f;
        #pragma unroll
        for (int c = 0; c < 9; ++c) {
            const int j = part * 9 + c;
            const float gj = gw[j];
            #pragma unroll
            for (int i = 0; i < GS; ++i)
                s = fmaf((float)sX[item * GS + i][j], gj, s);
        }
        s += __shfl_xor(s, 1);
        s += __shfl_xor(s, 2);
        s += __shfl_xor(s, 4);
        s += __shfl_xor(s, 8);
        if (part == 0) out[ibase + item] = s / nv[ibase + item];
    }
}

extern "C" void kernel_launch(void* const* d_in, const int* in_sizes, int n_in,
                              void* d_out, int out_size, void* d_ws, size_t ws_size,
                              hipStream_t stream) {
    const float* ops = (const float*)d_in[0];
    const float* adj = (const float*)d_in[1];
    const float* nv  = (const float*)d_in[2];
    const float* w10 = (const float*)d_in[3];
    const float* w20 = (const float*)d_in[4];
    const float* w11 = (const float*)d_in[5];
    const float* w21 = (const float*)d_in[6];
    const float* w12 = (const float*)d_in[7];
    const float* w22 = (const float*)d_in[8];
    const float* fc1 = (const float*)d_in[9];
    const float* fc2 = (const float*)d_in[10];

    _Float16* wt = (_Float16*)d_ws;                              // 248832 B
    float*    g  = (float*)((char*)d_ws + (size_t)WT_HALFS * 2); // 576 B

    prep_kernel<<<WT_HALFS / 256 + 1, 256, 0, stream>>>(w10, w20, w11, w21, w12, w22,
                                                        fc1, fc2, wt, g);
    gcn_mfma<<<65536 / NI, 256, 0, stream>>>(ops, adj, nv, wt, g, (float*)d_out);
}

// Round 6
// 324.446 us; speedup vs baseline: 15.9844x; 1.1013x over previous
//
#include <hip/hip_runtime.h>

// Fused 3-layer GCN (GS=7, H=144) + pool + fc, B=65536.  Round 6.
// R5 was stalled (88% idle) on scattered A-fragment loads: lane-stride 288 B
// meant 64 distinct cache lines per global_load_dwordx4, serializing in the
// TA/L1 path. R6: FRAGMENT-LINEAR weight layout — prep_kernel stores wt in
// exact MFMA A-fragment order, so each fragment load is one fully-coalesced
// 1 KB transaction (16 B/lane, lanes consecutive). Also __launch_bounds__
// (256,5): LDS 31.2 KB allows 5 blocks/CU (R5's ,3 was self-capping at 43%).
// wt layout: [l][ (chunk*3+tile)*9 + ks ][lane][j]  (512 halfs per frag-block)
//   element = Wt[n][k], n = chunk*96+tile*32+(lane&31) (n=2j+p interleaves
//   W1/W2), k = ks*16+(lane>>5)*8+j.
// MFMA mapping (verified R3-R5): A[n][k]=Wt, B[k][m]=X -> D[n][m]=T[m][n];
// C/D: col=lane&31 (=m), row=(reg&3)+8*(reg>>2)+4*(lane>>5) (=n).

typedef _Float16 half8   __attribute__((ext_vector_type(8)));
typedef _Float16 half4_t __attribute__((ext_vector_type(4)));
typedef _Float16 half2_t __attribute__((ext_vector_type(2)));
typedef float    floatx16 __attribute__((ext_vector_type(16)));

constexpr int GS = 7;
constexpr int NI = 8;           // graphs per block
constexpr int MROWS = NI * GS;  // 56
constexpr int H = 144;
constexpr int LSTRIDE = 81 * 512;         // 41472 halfs per layer (81 frag-blocks)
constexpr int WT_HALFS = 3 * LSTRIDE;     // 124416

static __device__ inline half8 bc(_Float16 v) {
    half8 h = {v, v, v, v, v, v, v, v};
    return h;
}

// ---------------- prologue: weights -> fragment-linear fp16, g = fc2 @ fc1 ----------------
__global__ void prep_kernel(const float* __restrict__ w10, const float* __restrict__ w20,
                            const float* __restrict__ w11, const float* __restrict__ w21,
                            const float* __restrict__ w12, const float* __restrict__ w22,
                            const float* __restrict__ fc1, const float* __restrict__ fc2,
                            _Float16* __restrict__ wt, float* __restrict__ g)
{
    const int gidx = blockIdx.x * 256 + threadIdx.x;
    if (gidx < WT_HALFS) {
        const int l    = gidx / LSTRIDE;
        const int r    = gidx - l * LSTRIDE;
        const int frag = r >> 9;            // 512 halfs per fragment-block
        const int wi   = r & 511;
        const int lane = wi >> 3;
        const int j8   = wi & 7;
        const int c    = frag / 27;
        const int rem  = frag - c * 27;
        const int t    = rem / 9;
        const int ks   = rem - t * 9;
        const int n    = c * 96 + t * 32 + (lane & 31);   // interleaved out-col
        const int k    = ks * 16 + (lane >> 5) * 8 + j8;  // in-dim
        const int jw   = n >> 1;
        const int p    = n & 1;
        const float* W = (l == 0) ? (p ? w20 : w10)
                       : (l == 1) ? (p ? w21 : w11)
                                  : (p ? w22 : w12);
        const int K = (l == 0) ? 5 : 144;
        wt[gidx] = (k < K) ? (_Float16)W[k * H + jw] : (_Float16)0.f;
    }
    if (blockIdx.x == WT_HALFS / 256 && threadIdx.x < H) {
        const int j = threadIdx.x;
        float s = 0.f;
        for (int o = 0; o < 128; ++o) s = fmaf(fc2[o], fc1[o * H + j], s);
        g[j] = s;
    }
}

__global__ __launch_bounds__(256, 5)
void gcn_mfma(const float* __restrict__ ops, const float* __restrict__ adj,
              const float* __restrict__ nv,
              const _Float16* __restrict__ wt, const float* __restrict__ gw,
              float* __restrict__ out)
{
    __shared__ __align__(16) _Float16 sX[64][152];     // 19456 B (rows 56-63: sA)
    __shared__ __align__(16) _Float16 sT[MROWS][104];  // 11648 B   total 31104 B

    _Float16 (*sA)[2][GS][8] = (_Float16(*)[2][GS][8])&sX[MROWS][0];  // sX pad rows
    float (*adjd)[GS][GS] = (float(*)[GS][GS])&sT[0][0];              // prologue-only

    const int tid  = threadIdx.x;
    const int lane = tid & 63;
    const int wv   = tid >> 6;
    const int ibase = blockIdx.x * NI;

    // ---------------- per-block prologue: stage X (fp16), adjacency matrices ----------------
    if (tid < MROWS) {
        const int item = tid / GS, r = tid % GS;
        const float* orow = ops + ((size_t)(ibase + item) * GS + r) * 5;
        half8 h = bc((_Float16)0);
        h[0] = (_Float16)orow[0]; h[1] = (_Float16)orow[1]; h[2] = (_Float16)orow[2];
        h[3] = (_Float16)orow[3]; h[4] = (_Float16)orow[4];
        *(half8*)&sX[tid][0] = h;
        *(half8*)&sX[tid][8] = bc((_Float16)0);   // layer-0 K pad

        const float* arow = adj + ((size_t)(ibase + item) * GS + r) * GS;
        float a[GS]; float s = 0.f;
        #pragma unroll
        for (int c = 0; c < GS; ++c) { a[c] = arow[c] + (c == r ? 1.f : 0.f); s += a[c]; }
        const float is = 1.f / s;
        #pragma unroll
        for (int c = 0; c < GS; ++c) {
            const float v = a[c] * is;
            adjd[item][r][c] = v;
            sA[item][0][r][c] = (_Float16)v;
        }
        sA[item][0][r][7] = (_Float16)0.f;
    }
    __syncthreads();
    if (tid < MROWS) {    // inv_norm_adj = row_normalize(adj_d^T)
        const int item = tid / GS, r = tid % GS;
        float v[GS]; float s = 0.f;
        #pragma unroll
        for (int k = 0; k < GS; ++k) { v[k] = adjd[item][k][r]; s += v[k]; }
        const float is = 1.f / s;
        #pragma unroll
        for (int k = 0; k < GS; ++k) sA[item][1][r][k] = (_Float16)(v[k] * is);
        sA[item][1][r][7] = (_Float16)0.f;
    }
    __syncthreads();

    const int mt     = wv & 1;
    const int arow31 = lane & 31;
    const int mrow   = mt * 32 + arow31;
    const int khi    = (lane >> 5) * 8;
    const int t0     = (wv < 2) ? 0 : 2;    // wave's first n-tile in chunk
    const int tcnt   = (wv < 2) ? 2 : 1;    // n-tiles this wave owns

    // mix-thread identity (threads 0..191)
    const int mitem = tid / 24;
    const int mb    = tid - mitem * 24;     // jj-pair index 0..23
    half2_t xr0[GS], xr1[GS];               // x_new stash for chunks 0,1

    // ==================== 3 layers x 3 n-chunks ====================
    for (int layer = 0; layer < 3; ++layer) {
        const int nk = (layer == 0) ? 1 : 9;
        const _Float16* wl = wt + layer * LSTRIDE;

        // ---- B-fragments for this layer: x rows, once, into registers
        half8 bf[9];
        #pragma unroll
        for (int ks = 0; ks < 9; ++ks)
            if (ks < nk) bf[ks] = *(const half8*)&sX[mrow][ks * 16 + khi];

        for (int chunk = 0; chunk < 3; ++chunk) {
            // ---- GEMM: A from fragment-linear global (coalesced 1 KB/load)
            const _Float16* fb  = wl + (size_t)(chunk * 27) * 512 + (size_t)lane * 8;
            const _Float16* a0p = fb + (size_t)(t0 * 9) * 512;
            const _Float16* a1p = fb + (size_t)((t0 + 1) * 9) * 512;
            floatx16 acc0, acc1;
            #pragma unroll
            for (int i = 0; i < 16; ++i) { acc0[i] = 0.f; acc1[i] = 0.f; }
            #pragma unroll
            for (int ks = 0; ks < 9; ++ks) {
                if (ks < nk) {
                    const half8 a0 = *(const half8*)(a0p + (size_t)ks * 512);
                    acc0 = __builtin_amdgcn_mfma_f32_32x32x16_f16(a0, bf[ks], acc0, 0, 0, 0);
                    if (tcnt == 2) {
                        const half8 a1 = *(const half8*)(a1p + (size_t)ks * 512);
                        acc1 = __builtin_amdgcn_mfma_f32_32x32x16_f16(a1, bf[ks], acc1, 0, 0, 0);
                    }
                }
            }

            if (chunk) __syncthreads();   // Ba: prev mix done reading sT

            // ---- store T (packed half4), D row n = (reg&3)+8*(reg>>2)+4*(lane>>5)
            if (mrow < MROWS) {
                #pragma unroll
                for (int ti = 0; ti < 2; ++ti) {
                    if (ti < tcnt) {
                        const floatx16& A = ti ? acc1 : acc0;
                        const int ntl = (t0 + ti) * 32 + 4 * (lane >> 5);
                        #pragma unroll
                        for (int q = 0; q < 4; ++q) {
                            half4_t h;
                            h[0] = (_Float16)A[4 * q + 0];
                            h[1] = (_Float16)A[4 * q + 1];
                            h[2] = (_Float16)A[4 * q + 2];
                            h[3] = (_Float16)A[4 * q + 3];
                            *(half4_t*)&sT[mrow][ntl + 8 * q] = h;
                        }
                    }
                }
            }
            __syncthreads();   // Bb: T visible to mixers

            // ---- mixing (chunk-local 48 cols): x = 0.5*(relu(nA@T1)+relu(iA@T2))
            // sT row layout: local n = 2*jj + p  (p=0 -> T1, p=1 -> T2), jj in [0,48)
            if (tid < 192) {
                const int row0 = mitem * GS;
                half2_t e[GS], o[GS];
                #pragma unroll
                for (int k = 0; k < GS; ++k) {
                    const half4_t c = *(const half4_t*)&sT[row0 + k][mb * 4];
                    e[k] = __builtin_shufflevector(c, c, 0, 2);   // T1 cols jj=2mb,2mb+1
                    o[k] = __builtin_shufflevector(c, c, 1, 3);   // T2 cols
                }
                #pragma unroll
                for (int i = 0; i < GS; ++i) {
                    const half8 aN = *(const half8*)&sA[mitem][0][i][0];
                    const half8 aI = *(const half8*)&sA[mitem][1][i][0];
                    half2_t s1 = {(_Float16)0, (_Float16)0};
                    half2_t s2 = {(_Float16)0, (_Float16)0};
                    #pragma unroll
                    for (int k = 0; k < GS; ++k) {
                        const half2_t bN = {aN[k], aN[k]};
                        const half2_t bI = {aI[k], aI[k]};
                        s1 += bN * e[k];
                        s2 += bI * o[k];
                    }
                    if (s1[0] < (_Float16)0) s1[0] = (_Float16)0;
                    if (s1[1] < (_Float16)0) s1[1] = (_Float16)0;
                    if (s2[0] < (_Float16)0) s2[0] = (_Float16)0;
                    if (s2[1] < (_Float16)0) s2[1] = (_Float16)0;
                    const half2_t x = (s1 + s2) * (half2_t){(_Float16)0.5f, (_Float16)0.5f};
                    if (chunk == 0)      xr0[i] = x;
                    else if (chunk == 1) xr1[i] = x;
                    else {
                        // all GEMM B-reads of this layer were done at layer start
                        *(half2_t*)&sX[row0 + i][96 + 2 * mb] = x;
                        *(half2_t*)&sX[row0 + i][      2 * mb] = xr0[i];
                        *(half2_t*)&sX[row0 + i][ 48 + 2 * mb] = xr1[i];
                    }
                }
            }
        } // chunk
        __syncthreads();   // Bc: new sX visible for next layer's B-frag loads / pool
    } // layer

    // ==================== pool + (fc2@fc1) dot ====================
    if (tid < NI * 16) {
        const int item = tid >> 4, part = tid & 15;
        float s = 0.f;
        #pragma unroll
        for (int c = 0; c < 9; ++c) {
            const int j = part * 9 + c;
            const float gj = gw[j];
            #pragma unroll
            for (int i = 0; i < GS; ++i)
                s = fmaf((float)sX[item * GS + i][j], gj, s);
        }
        s += __shfl_xor(s, 1);
        s += __shfl_xor(s, 2);
        s += __shfl_xor(s, 4);
        s += __shfl_xor(s, 8);
        if (part == 0) out[ibase + item] = s / nv[ibase + item];
    }
}

extern "C" void kernel_launch(void* const* d_in, const int* in_sizes, int n_in,
                              void* d_out, int out_size, void* d_ws, size_t ws_size,
                              hipStream_t stream) {
    const float* ops = (const float*)d_in[0];
    const float* adj = (const float*)d_in[1];
    const float* nv  = (const float*)d_in[2];
    const float* w10 = (const float*)d_in[3];
    const float* w20 = (const float*)d_in[4];
    const float* w11 = (const float*)d_in[5];
    const float* w21 = (const float*)d_in[6];
    const float* w12 = (const float*)d_in[7];
    const float* w22 = (const float*)d_in[8];
    const float* fc1 = (const float*)d_in[9];
    const float* fc2 = (const float*)d_in[10];

    _Float16* wt = (_Float16*)d_ws;                              // 248832 B
    float*    g  = (float*)((char*)d_ws + (size_t)WT_HALFS * 2); // 576 B

    prep_kernel<<<WT_HALFS / 256 + 1, 256, 0, stream>>>(w10, w20, w11, w21, w12, w22,
                                                        fc1, fc2, wt, g);
    gcn_mfma<<<65536 / NI, 256, 0, stream>>>(ops, adj, nv, wt, g, (float*)d_out);
}

// Round 7
// 280.568 us; speedup vs baseline: 18.4843x; 1.1564x over previous
//
#include <hip/hip_runtime.h>

// Fused 3-layer GCN (GS=7, H=144) + pool + fc, B=65536.  Round 7.
// Key algebra: relu(nA@(x@W)) == relu((nA@x)@W)  (matmul associativity), so
// pre-mix Xn = nA@x, Xi = iA@x BEFORE the GEMM; then
//   x_new = 0.5*(relu(Xn@W1) + relu(Xi@W2))
// is an element-wise epilogue applied directly to the MFMA accumulators ->
// the sT round-trip and post-GEMM mixing of R4-R6 are deleted. 2 barriers
// per layer (post-premix, post-epilogue).
// Weights (prep_kernel, d_ws) fragment-linear, non-interleaved:
//   wt[l][p][nt][ks][lane][j8], n = nt*32+(lane&31) (0..159, >=144 zero),
//   k = ks*16+(lane>>5)*8+j8.  1 KB per fragment, fully coalesced.
// MFMA mapping (verified R3-R6): A[n][k]=Wt, B[k][m]=Xmix -> D[n][m];
// A/B: lane holds row/col lane&31, 8 contiguous k at (lane>>5)*8;
// C/D: col=lane&31 (=m), row=(reg&3)+8*(reg>>2)+4*(lane>>5) (=n).
// LDS: sX + sXn + sXi (56x152 fp16 each) + sA = 52.9 KB -> 3 blocks/CU.

typedef _Float16 half8   __attribute__((ext_vector_type(8)));
typedef _Float16 half4_t __attribute__((ext_vector_type(4)));
typedef float    floatx16 __attribute__((ext_vector_type(16)));

constexpr int GS = 7;
constexpr int NI = 8;           // graphs per block
constexpr int MROWS = NI * GS;  // 56
constexpr int H = 144;
constexpr int LSTRIDE = 2 * 5 * 9 * 512;  // 46080 halfs per layer
constexpr int WT_HALFS = 3 * LSTRIDE;     // 138240

static __device__ inline half8 bc(_Float16 v) {
    half8 h = {v, v, v, v, v, v, v, v};
    return h;
}

// ---------------- prologue: weights -> fragment-linear fp16, g = fc2 @ fc1 ----------------
__global__ void prep_kernel(const float* __restrict__ w10, const float* __restrict__ w20,
                            const float* __restrict__ w11, const float* __restrict__ w21,
                            const float* __restrict__ w12, const float* __restrict__ w22,
                            const float* __restrict__ fc1, const float* __restrict__ fc2,
                            _Float16* __restrict__ wt, float* __restrict__ g)
{
    const int gidx = blockIdx.x * 256 + threadIdx.x;
    if (gidx < WT_HALFS) {
        const int l    = gidx / LSTRIDE;
        const int r    = gidx - l * LSTRIDE;
        const int frag = r >> 9;            // 512 halfs per fragment-block
        const int wi   = r & 511;
        const int lane = wi >> 3;
        const int j8   = wi & 7;
        const int p    = frag / 45;         // 0 -> W1, 1 -> W2
        const int rem  = frag - p * 45;
        const int nt   = rem / 9;
        const int ks   = rem - nt * 9;
        const int n    = nt * 32 + (lane & 31);           // out-col 0..159
        const int k    = ks * 16 + (lane >> 5) * 8 + j8;  // in-dim 0..143
        const float* W = (l == 0) ? (p ? w20 : w10)
                       : (l == 1) ? (p ? w21 : w11)
                                  : (p ? w22 : w12);
        const int K = (l == 0) ? 5 : 144;
        wt[gidx] = (n < H && k < K) ? (_Float16)W[k * H + n] : (_Float16)0.f;
    }
    if (blockIdx.x == WT_HALFS / 256 && threadIdx.x < H) {
        const int j = threadIdx.x;
        float s = 0.f;
        for (int o = 0; o < 128; ++o) s = fmaf(fc2[o], fc1[o * H + j], s);
        g[j] = s;
    }
}

__global__ __launch_bounds__(256, 3)
void gcn_mfma(const float* __restrict__ ops, const float* __restrict__ adj,
              const float* __restrict__ nv,
              const _Float16* __restrict__ wt, const float* __restrict__ gw,
              float* __restrict__ out)
{
    __shared__ __align__(16) _Float16 sX [MROWS][152];   // 17024 B
    __shared__ __align__(16) _Float16 sXn[MROWS][152];   // 17024 B
    __shared__ __align__(16) _Float16 sXi[MROWS][152];   // 17024 B
    __shared__ __align__(16) _Float16 sAh[NI][2][GS][8]; //  1792 B  total 52864 B

    float (*adjd)[GS][GS] = (float(*)[GS][GS])&sXn[0][0];   // prologue-only scratch

    const int tid  = threadIdx.x;
    const int lane = tid & 63;
    const int wv   = tid >> 6;
    const int ibase = blockIdx.x * NI;

    // ---------------- per-block prologue: stage X (fp16), adjacency matrices ----------------
    if (tid < MROWS) {
        const int item = tid / GS, r = tid % GS;
        const float* orow = ops + ((size_t)(ibase + item) * GS + r) * 5;
        half8 h = bc((_Float16)0);
        h[0] = (_Float16)orow[0]; h[1] = (_Float16)orow[1]; h[2] = (_Float16)orow[2];
        h[3] = (_Float16)orow[3]; h[4] = (_Float16)orow[4];
        *(half8*)&sX[tid][0] = h;
        *(half8*)&sX[tid][8] = bc((_Float16)0);   // layer-0 K pad (k=5..15)

        const float* arow = adj + ((size_t)(ibase + item) * GS + r) * GS;
        float a[GS]; float s = 0.f;
        #pragma unroll
        for (int c = 0; c < GS; ++c) { a[c] = arow[c] + (c == r ? 1.f : 0.f); s += a[c]; }
        const float is = 1.f / s;
        #pragma unroll
        for (int c = 0; c < GS; ++c) {
            const float v = a[c] * is;
            adjd[item][r][c] = v;
            sAh[item][0][r][c] = (_Float16)v;
        }
        sAh[item][0][r][7] = (_Float16)0.f;
    }
    __syncthreads();
    if (tid < MROWS) {    // inv_norm_adj = row_normalize(adj_d^T)
        const int item = tid / GS, r = tid % GS;
        float v[GS]; float s = 0.f;
        #pragma unroll
        for (int k = 0; k < GS; ++k) { v[k] = adjd[item][k][r]; s += v[k]; }
        const float is = 1.f / s;
        #pragma unroll
        for (int k = 0; k < GS; ++k) sAh[item][1][r][k] = (_Float16)(v[k] * is);
        sAh[item][1][r][7] = (_Float16)0.f;
    }
    __syncthreads();

    const int mt     = wv & 1;
    const int arow31 = lane & 31;
    const int mrow   = mt * 32 + arow31;                 // 0..63; >=56 invalid
    const int mrowc  = (mrow < MROWS) ? mrow : 0;        // clamped for LDS reads
    const int khi    = (lane >> 5) * 8;
    const int ntbase = (wv < 2) ? 0 : 3;                 // wave's n-tiles
    const int ntcnt  = (wv < 2) ? 3 : 2;

    // ==================== 3 layers ====================
    for (int layer = 0; layer < 3; ++layer) {
        const int nk = (layer == 0) ? 1 : 9;
        const _Float16* wl = wt + (size_t)layer * LSTRIDE;

        // ---- pre-mix: Xn = nA@x, Xi = iA@x  (shared x reads, all threads)
        if (layer == 0) {
            for (int u = tid; u < MROWS * 2; u += 256) {
                const int row = u >> 1, cb = u & 1;
                const int item = row / GS, rr = row - item * GS;
                const int c0 = cb * 8;
                const half8 aN = *(const half8*)&sAh[item][0][rr][0];
                const half8 aI = *(const half8*)&sAh[item][1][rr][0];
                half8 an = bc((_Float16)0), ai = bc((_Float16)0);
                #pragma unroll
                for (int j = 0; j < GS; ++j) {
                    const half8 xj = *(const half8*)&sX[item * GS + j][c0];
                    an += bc(aN[j]) * xj;
                    ai += bc(aI[j]) * xj;
                }
                *(half8*)&sXn[row][c0] = an;
                *(half8*)&sXi[row][c0] = ai;
            }
        } else {
            for (int u = tid; u < MROWS * 18; u += 256) {
                const int row = u / 18, cb = u - row * 18;
                const int item = row / GS, rr = row - item * GS;
                const int c0 = cb * 8;
                const half8 aN = *(const half8*)&sAh[item][0][rr][0];
                const half8 aI = *(const half8*)&sAh[item][1][rr][0];
                half8 an = bc((_Float16)0), ai = bc((_Float16)0);
                #pragma unroll
                for (int j = 0; j < GS; ++j) {
                    const half8 xj = *(const half8*)&sX[item * GS + j][c0];
                    an += bc(aN[j]) * xj;
                    ai += bc(aI[j]) * xj;
                }
                *(half8*)&sXn[row][c0] = an;
                *(half8*)&sXi[row][c0] = ai;
            }
        }
        __syncthreads();   // B1: Xn/Xi ready; all sX reads of this layer done

        // ---- B-fragments hoisted once per layer
        half8 bn[9], bi[9];
        #pragma unroll
        for (int ks = 0; ks < 9; ++ks) {
            if (ks < nk) {
                bn[ks] = *(const half8*)&sXn[mrowc][ks * 16 + khi];
                bi[ks] = *(const half8*)&sXi[mrowc][ks * 16 + khi];
            }
        }

        // ---- GEMM + in-register epilogue, store x_new straight to sX
        for (int t = 0; t < ntcnt; ++t) {
            const int nt = ntbase + t;
            const _Float16* a1p = wl + (size_t)(nt * 9) * 512 + (size_t)lane * 8;
            const _Float16* a2p = a1p + (size_t)(45 * 512);
            floatx16 acc1, acc2;
            #pragma unroll
            for (int i = 0; i < 16; ++i) { acc1[i] = 0.f; acc2[i] = 0.f; }
            #pragma unroll
            for (int ks = 0; ks < 9; ++ks) {
                if (ks < nk) {
                    const half8 a1 = *(const half8*)(a1p + (size_t)ks * 512);
                    acc1 = __builtin_amdgcn_mfma_f32_32x32x16_f16(a1, bn[ks], acc1, 0, 0, 0);
                    const half8 a2 = *(const half8*)(a2p + (size_t)ks * 512);
                    acc2 = __builtin_amdgcn_mfma_f32_32x32x16_f16(a2, bi[ks], acc2, 0, 0, 0);
                }
            }
            // epilogue: x = 0.5*(relu(acc1)+relu(acc2)), D row n -> sX col
            if (mrow < MROWS) {
                #pragma unroll
                for (int q = 0; q < 4; ++q) {
                    const int n0 = nt * 32 + 4 * (lane >> 5) + 8 * q;
                    if (n0 < H) {
                        half4_t h;
                        #pragma unroll
                        for (int i = 0; i < 4; ++i) {
                            const float v1 = acc1[4 * q + i] > 0.f ? acc1[4 * q + i] : 0.f;
                            const float v2 = acc2[4 * q + i] > 0.f ? acc2[4 * q + i] : 0.f;
                            h[i] = (_Float16)(0.5f * (v1 + v2));
                        }
                        *(half4_t*)&sX[mrow][n0] = h;
                    }
                }
            }
        }
        __syncthreads();   // B2: x_new visible (next premix / pool)
    } // layer

    // ==================== pool + (fc2@fc1) dot ====================
    if (tid < NI * 16) {
        const int item = tid >> 4, part = tid & 15;
        float s = 0.f;
        #pragma unroll
        for (int c = 0; c < 9; ++c) {
            const int j = part * 9 + c;
            const float gj = gw[j];
            #pragma unroll
            for (int i = 0; i < GS; ++i)
                s = fmaf((float)sX[item * GS + i][j], gj, s);
        }
        s += __shfl_xor(s, 1);
        s += __shfl_xor(s, 2);
        s += __shfl_xor(s, 4);
        s += __shfl_xor(s, 8);
        if (part == 0) out[ibase + item] = s / nv[ibase + item];
    }
}

extern "C" void kernel_launch(void* const* d_in, const int* in_sizes, int n_in,
                              void* d_out, int out_size, void* d_ws, size_t ws_size,
                              hipStream_t stream) {
    const float* ops = (const float*)d_in[0];
    const float* adj = (const float*)d_in[1];
    const float* nv  = (const float*)d_in[2];
    const float* w10 = (const float*)d_in[3];
    const float* w20 = (const float*)d_in[4];
    const float* w11 = (const float*)d_in[5];
    const float* w21 = (const float*)d_in[6];
    const float* w12 = (const float*)d_in[7];
    const float* w22 = (const float*)d_in[8];
    const float* fc1 = (const float*)d_in[9];
    const float* fc2 = (const float*)d_in[10];

    _Float16* wt = (_Float16*)d_ws;                              // 276480 B
    float*    g  = (float*)((char*)d_ws + (size_t)WT_HALFS * 2); // 576 B

    prep_kernel<<<WT_HALFS / 256 + 1, 256, 0, stream>>>(w10, w20, w11, w21, w12, w22,
                                                        fc1, fc2, wt, g);
    gcn_mfma<<<65536 / NI, 256, 0, stream>>>(ops, adj, nv, wt, g, (float*)d_out);
}

// Round 8
// 270.879 us; speedup vs baseline: 19.1454x; 1.0358x over previous
//
#include <hip/hip_runtime.h>

// Fused 3-layer GCN (GS=7, H=144) + pool + fc, B=65536.  Round 8.
// R7 kernel was ~61% issue-utilized with VALU inflated by runtime control
// flow (ks<nk predication, n0<H guards, runtime tile counts), and ~54 us sat
// in an uncoalesced prep kernel + dispatch gap. R8:
//  - prep_kernel: one thread per 8-half fragment slice, lane-coalesced reads
//    over n (128 B lines), b128 stores. 69 blocks, ~5 us.
//  - gcn_mfma: layer 0 peeled (NK=1), layers 1-2 NK=9 templated; wave-static
//    tile sets fully unrolled; tile-4 column guard folded at compile time.
// Algorithm unchanged from R7 (associativity premix):
//   Xn = nA@x, Xi = iA@x;  x_new = 0.5*(relu(Xn@W1) + relu(Xi@W2))
// wt layout (d_ws): [l][p][nt][ks][lane][j8], n = nt*32+(lane&31) (>=144 pad0),
//   k = ks*16+(lane>>5)*8+j8.  1 KB per fragment, coalesced.
// MFMA mapping (verified R3-R7): A[n][k]=Wt, B[k][m]=Xmix -> D[n][m];
// C/D: col=lane&31 (=m), row=(reg&3)+8*(reg>>2)+4*(lane>>5) (=n).
// LDS: sX + sXn + sXi (56x152 fp16) + sA = 52.9 KB -> 3 blocks/CU.

typedef _Float16 half8   __attribute__((ext_vector_type(8)));
typedef _Float16 half4_t __attribute__((ext_vector_type(4)));
typedef float    floatx16 __attribute__((ext_vector_type(16)));

constexpr int GS = 7;
constexpr int NI = 8;           // graphs per block
constexpr int MROWS = NI * GS;  // 56
constexpr int H = 144;
constexpr int LSTRIDE = 2 * 5 * 9 * 512;  // 46080 halfs per layer
constexpr int WT_HALFS = 3 * LSTRIDE;     // 138240
constexpr int FRAGS = 3 * 90 * 64;        // thread-slices in prep (17280)

static __device__ inline half8 bc(_Float16 v) {
    half8 h = {v, v, v, v, v, v, v, v};
    return h;
}

// ---------------- prologue: weights -> fragment-linear fp16, g = fc2 @ fc1 ----------------
__global__ void prep_kernel(const float* __restrict__ w10, const float* __restrict__ w20,
                            const float* __restrict__ w11, const float* __restrict__ w21,
                            const float* __restrict__ w12, const float* __restrict__ w22,
                            const float* __restrict__ fc1, const float* __restrict__ fc2,
                            _Float16* __restrict__ wt, float* __restrict__ g)
{
    if (blockIdx.x == 68) {             // g = fc2 @ fc1 (both linear, no act)
        const int j = threadIdx.x;
        if (j < H) {
            float s = 0.f;
            for (int o = 0; o < 128; ++o) s = fmaf(fc2[o], fc1[o * H + j], s);
            g[j] = s;
        }
        return;
    }
    const int t = blockIdx.x * 256 + threadIdx.x;
    if (t >= FRAGS) return;
    const int l    = t / (90 * 64);
    const int r    = t - l * (90 * 64);
    const int frag = r >> 6;            // 0..89
    const int lane = r & 63;
    const int p    = frag / 45;         // 0 -> W1, 1 -> W2
    const int rem  = frag - p * 45;
    const int nt   = rem / 9;
    const int ks   = rem - nt * 9;
    const int n    = nt * 32 + (lane & 31);           // out-col 0..159
    const int k0   = ks * 16 + (lane >> 5) * 8;       // in-dim base
    const float* W = (l == 0) ? (p ? w20 : w10)
                   : (l == 1) ? (p ? w21 : w11)
                              : (p ? w22 : w12);
    const int K = (l == 0) ? 5 : 144;
    half8 h = bc((_Float16)0);
    #pragma unroll
    for (int j = 0; j < 8; ++j) {
        const int k = k0 + j;
        if (n < H && k < K) h[j] = (_Float16)W[k * H + n];   // lanes coalesce over n
    }
    *(half8*)(wt + (size_t)l * LSTRIDE + (size_t)frag * 512 + (size_t)lane * 8) = h;
}

// ---- one n-tile: dual GEMM + relu/avg epilogue, store x_new to sX ----
template<int NK, int NT>
__device__ __forceinline__ void gemm_store(const _Float16* __restrict__ wl,
                                           const half8* bn, const half8* bi,
                                           const int lane, const int mrow,
                                           _Float16 (*sX)[152])
{
    const _Float16* a1p = wl + (size_t)(NT * 9) * 512 + (size_t)lane * 8;
    const _Float16* a2p = a1p + (size_t)(45 * 512);
    floatx16 acc1, acc2;
    #pragma unroll
    for (int i = 0; i < 16; ++i) { acc1[i] = 0.f; acc2[i] = 0.f; }
    #pragma unroll
    for (int ks = 0; ks < NK; ++ks) {
        const half8 a1 = *(const half8*)(a1p + (size_t)ks * 512);
        acc1 = __builtin_amdgcn_mfma_f32_32x32x16_f16(a1, bn[ks], acc1, 0, 0, 0);
        const half8 a2 = *(const half8*)(a2p + (size_t)ks * 512);
        acc2 = __builtin_amdgcn_mfma_f32_32x32x16_f16(a2, bi[ks], acc2, 0, 0, 0);
    }
    if (mrow < MROWS) {
        #pragma unroll
        for (int q = 0; q < 4; ++q) {
            if (NT < 4 || q < 2) {                     // static: tile 4 cols 144+ dropped
                const int n0 = NT * 32 + 4 * (lane >> 5) + 8 * q;
                half4_t h;
                #pragma unroll
                for (int i = 0; i < 4; ++i) {
                    const float v1 = acc1[4 * q + i] > 0.f ? acc1[4 * q + i] : 0.f;
                    const float v2 = acc2[4 * q + i] > 0.f ? acc2[4 * q + i] : 0.f;
                    h[i] = (_Float16)(0.5f * (v1 + v2));
                }
                *(half4_t*)&sX[mrow][n0] = h;
            }
        }
    }
}

__global__ __launch_bounds__(256, 3)
void gcn_mfma(const float* __restrict__ ops, const float* __restrict__ adj,
              const float* __restrict__ nv,
              const _Float16* __restrict__ wt, const float* __restrict__ gw,
              float* __restrict__ out)
{
    __shared__ __align__(16) _Float16 sX [MROWS][152];   // 17024 B
    __shared__ __align__(16) _Float16 sXn[MROWS][152];   // 17024 B
    __shared__ __align__(16) _Float16 sXi[MROWS][152];   // 17024 B
    __shared__ __align__(16) _Float16 sAh[NI][2][GS][8]; //  1792 B  total 52864 B

    float (*adjd)[GS][GS] = (float(*)[GS][GS])&sXn[0][0];   // prologue-only scratch

    const int tid  = threadIdx.x;
    const int lane = tid & 63;
    const int wv   = tid >> 6;
    const int ibase = blockIdx.x * NI;

    // ---------------- per-block prologue: stage X (fp16), adjacency matrices ----------------
    if (tid < MROWS) {
        const int item = tid / GS, r = tid % GS;
        const float* orow = ops + ((size_t)(ibase + item) * GS + r) * 5;
        half8 h = bc((_Float16)0);
        h[0] = (_Float16)orow[0]; h[1] = (_Float16)orow[1]; h[2] = (_Float16)orow[2];
        h[3] = (_Float16)orow[3]; h[4] = (_Float16)orow[4];
        *(half8*)&sX[tid][0] = h;
        *(half8*)&sX[tid][8] = bc((_Float16)0);   // layer-0 K pad (k=5..15)

        const float* arow = adj + ((size_t)(ibase + item) * GS + r) * GS;
        float a[GS]; float s = 0.f;
        #pragma unroll
        for (int c = 0; c < GS; ++c) { a[c] = arow[c] + (c == r ? 1.f : 0.f); s += a[c]; }
        const float is = 1.f / s;
        #pragma unroll
        for (int c = 0; c < GS; ++c) {
            const float v = a[c] * is;
            adjd[item][r][c] = v;
            sAh[item][0][r][c] = (_Float16)v;
        }
        sAh[item][0][r][7] = (_Float16)0.f;
    }
    __syncthreads();
    if (tid < MROWS) {    // inv_norm_adj = row_normalize(adj_d^T)
        const int item = tid / GS, r = tid % GS;
        float v[GS]; float s = 0.f;
        #pragma unroll
        for (int k = 0; k < GS; ++k) { v[k] = adjd[item][k][r]; s += v[k]; }
        const float is = 1.f / s;
        #pragma unroll
        for (int k = 0; k < GS; ++k) sAh[item][1][r][k] = (_Float16)(v[k] * is);
        sAh[item][1][r][7] = (_Float16)0.f;
    }
    __syncthreads();

    const int mt     = wv & 1;
    const int arow31 = lane & 31;
    const int mrow   = mt * 32 + arow31;                 // 0..63; >=56 invalid
    const int mrowc  = (mrow < MROWS) ? mrow : 0;        // clamped for LDS reads
    const int khi    = (lane >> 5) * 8;

    // ==================== layer 0 (K=16, one k-step) ====================
    {
        // pre-mix cols 0..15 only
        for (int u = tid; u < MROWS * 2; u += 256) {
            const int row = u >> 1, cb = u & 1;
            const int item = row / GS, rr = row - item * GS;
            const int c0 = cb * 8;
            const half8 aN = *(const half8*)&sAh[item][0][rr][0];
            const half8 aI = *(const half8*)&sAh[item][1][rr][0];
            half8 an = bc((_Float16)0), ai = bc((_Float16)0);
            #pragma unroll
            for (int j = 0; j < GS; ++j) {
                const half8 xj = *(const half8*)&sX[item * GS + j][c0];
                an += bc(aN[j]) * xj;
                ai += bc(aI[j]) * xj;
            }
            *(half8*)&sXn[row][c0] = an;
            *(half8*)&sXi[row][c0] = ai;
        }
        __syncthreads();

        half8 bn[1], bi[1];
        bn[0] = *(const half8*)&sXn[mrowc][khi];
        bi[0] = *(const half8*)&sXi[mrowc][khi];

        if (wv < 2) {
            gemm_store<1, 0>(wt, bn, bi, lane, mrow, sX);
            gemm_store<1, 1>(wt, bn, bi, lane, mrow, sX);
            gemm_store<1, 2>(wt, bn, bi, lane, mrow, sX);
        } else {
            gemm_store<1, 3>(wt, bn, bi, lane, mrow, sX);
            gemm_store<1, 4>(wt, bn, bi, lane, mrow, sX);
        }
        __syncthreads();
    }

    // ==================== layers 1,2 (K=144, nine k-steps) ====================
    for (int layer = 1; layer < 3; ++layer) {
        const _Float16* wl = wt + (size_t)layer * LSTRIDE;

        // pre-mix full width
        for (int u = tid; u < MROWS * 18; u += 256) {
            const int row = u / 18, cb = u - row * 18;
            const int item = row / GS, rr = row - item * GS;
            const int c0 = cb * 8;
            const half8 aN = *(const half8*)&sAh[item][0][rr][0];
            const half8 aI = *(const half8*)&sAh[item][1][rr][0];
            half8 an = bc((_Float16)0), ai = bc((_Float16)0);
            #pragma unroll
            for (int j = 0; j < GS; ++j) {
                const half8 xj = *(const half8*)&sX[item * GS + j][c0];
                an += bc(aN[j]) * xj;
                ai += bc(aI[j]) * xj;
            }
            *(half8*)&sXn[row][c0] = an;
            *(half8*)&sXi[row][c0] = ai;
        }
        __syncthreads();

        half8 bn[9], bi[9];
        #pragma unroll
        for (int ks = 0; ks < 9; ++ks) {
            bn[ks] = *(const half8*)&sXn[mrowc][ks * 16 + khi];
            bi[ks] = *(const half8*)&sXi[mrowc][ks * 16 + khi];
        }

        if (wv < 2) {
            gemm_store<9, 0>(wl, bn, bi, lane, mrow, sX);
            gemm_store<9, 1>(wl, bn, bi, lane, mrow, sX);
            gemm_store<9, 2>(wl, bn, bi, lane, mrow, sX);
        } else {
            gemm_store<9, 3>(wl, bn, bi, lane, mrow, sX);
            gemm_store<9, 4>(wl, bn, bi, lane, mrow, sX);
        }
        __syncthreads();
    }

    // ==================== pool + (fc2@fc1) dot ====================
    if (tid < NI * 16) {
        const int item = tid >> 4, part = tid & 15;
        float s = 0.f;
        #pragma unroll
        for (int c = 0; c < 9; ++c) {
            const int j = part * 9 + c;
            const float gj = gw[j];
            #pragma unroll
            for (int i = 0; i < GS; ++i)
                s = fmaf((float)sX[item * GS + i][j], gj, s);
        }
        s += __shfl_xor(s, 1);
        s += __shfl_xor(s, 2);
        s += __shfl_xor(s, 4);
        s += __shfl_xor(s, 8);
        if (part == 0) out[ibase + item] = s / nv[ibase + item];
    }
}

extern "C" void kernel_launch(void* const* d_in, const int* in_sizes, int n_in,
                              void* d_out, int out_size, void* d_ws, size_t ws_size,
                              hipStream_t stream) {
    const float* ops = (const float*)d_in[0];
    const float* adj = (const float*)d_in[1];
    const float* nv  = (const float*)d_in[2];
    const float* w10 = (const float*)d_in[3];
    const float* w20 = (const float*)d_in[4];
    const float* w11 = (const float*)d_in[5];
    const float* w21 = (const float*)d_in[6];
    const float* w12 = (const float*)d_in[7];
    const float* w22 = (const float*)d_in[8];
    const float* fc1 = (const float*)d_in[9];
    const float* fc2 = (const float*)d_in[10];

    _Float16* wt = (_Float16*)d_ws;                              // 276480 B
    float*    g  = (float*)((char*)d_ws + (size_t)WT_HALFS * 2); // 576 B

    prep_kernel<<<69, 256, 0, stream>>>(w10, w20, w11, w21, w12, w22,
                                        fc1, fc2, wt, g);
    gcn_mfma<<<65536 / NI, 256, 0, stream>>>(ops, adj, nv, wt, g, (float*)d_out);
}